// Round 12
// baseline (277.632 us; speedup 1.0000x reference)
//
#include <hip/hip_runtime.h>
#include <hip/hip_bf16.h>
#include <cstdint>

// Problem constants (B=4, S=2048, D2=1024, DV=64, d_k=64)
#define S_LEN 2048
#define D2_   1024
#define DV_   64
#define NB_   4

typedef __bf16 bf16x8 __attribute__((ext_vector_type(8)));
typedef float  f32x4  __attribute__((ext_vector_type(4)));
typedef int    i32x4  __attribute__((ext_vector_type(4)));

// fp32 -> bf16 round-to-nearest-even
__device__ __forceinline__ unsigned short f2bf(float f) {
  union { float f; unsigned int u; } v; v.f = f;
  unsigned int r = v.u + 0x7fffu + ((v.u >> 16) & 1u);
  return (unsigned short)(r >> 16);
}

// async global->LDS, 16B per lane (global_load_lds_dwordx4)
__device__ __forceinline__ void async16(const unsigned short* g, unsigned short* l) {
  __builtin_amdgcn_global_load_lds(
      (__attribute__((address_space(1))) void*)g,
      (__attribute__((address_space(3))) void*)l,
      16, 0, 0);
}

// ---------------------------------------------------------------------------
// Kernel 1 (fused prep): per row r:
//   qn[r,:] = bf16( LN(q[r,:]) * 0.125 )      (1/sqrt(64) folded in)
//   kb[r,:] = bf16( k[r,:] )
//   blocks 0..3:  w2[d] = fc_w[d,:] . V       (rank-1 collapse of @fc_w.T)
//   blocks 0..31: zero rowsum[] (d_ws is poisoned 0xAA before every launch)
// ---------------------------------------------------------------------------
__global__ void __launch_bounds__(256) prep_kernel(
    const float* __restrict__ q, const float* __restrict__ k,
    const float* __restrict__ gam, const float* __restrict__ bet,
    const float* __restrict__ V, const float* __restrict__ fw,
    unsigned short* __restrict__ qn, unsigned short* __restrict__ kb,
    float* __restrict__ w2, float* __restrict__ rowsum) {
  const int row = blockIdx.x;
  const int t = threadIdx.x;

  if (row < 32) rowsum[row * 256 + t] = 0.0f;   // 8192 floats total

  const float4 x = ((const float4*)(q + (size_t)row * D2_))[t];
  float s  = x.x + x.y + x.z + x.w;
  float ss = x.x * x.x + x.y * x.y + x.z * x.z + x.w * x.w;
  #pragma unroll
  for (int o = 32; o > 0; o >>= 1) { s += __shfl_down(s, o); ss += __shfl_down(ss, o); }
  __shared__ float red[8];
  if ((t & 63) == 0) { red[t >> 6] = s; red[(t >> 6) + 4] = ss; }
  __syncthreads();
  const float tot  = red[0] + red[1] + red[2] + red[3];
  const float tots = red[4] + red[5] + red[6] + red[7];
  const float mu  = tot * (1.0f / D2_);
  const float var = tots * (1.0f / D2_) - mu * mu;
  const float rs  = rsqrtf(var + 1e-6f) * 0.125f;
  const float4 gv = ((const float4*)gam)[t];
  const float4 bv = ((const float4*)bet)[t];
  ushort4 o4;
  o4.x = f2bf((x.x - mu) * rs * gv.x + 0.125f * bv.x);
  o4.y = f2bf((x.y - mu) * rs * gv.y + 0.125f * bv.y);
  o4.z = f2bf((x.z - mu) * rs * gv.z + 0.125f * bv.z);
  o4.w = f2bf((x.w - mu) * rs * gv.w + 0.125f * bv.w);
  ((ushort4*)(qn + (size_t)row * D2_))[t] = o4;

  const float4 kx = ((const float4*)(k + (size_t)row * D2_))[t];
  ushort4 k4;
  k4.x = f2bf(kx.x); k4.y = f2bf(kx.y); k4.z = f2bf(kx.z); k4.w = f2bf(kx.w);
  ((ushort4*)(kb + (size_t)row * D2_))[t] = k4;

  if (row < 4) {
    const int d = row * 256 + t;
    const float4* r  = (const float4*)(fw + (size_t)d * DV_);
    const float4* vv = (const float4*)V;
    float acc = 0.f;
    #pragma unroll
    for (int j = 0; j < 16; ++j) {
      const float4 a = r[j], b = vv[j];
      acc += a.x * b.x + a.y * b.y + a.z * b.z + a.w * b.w;
    }
    w2[d] = acc;
  }
}

// ---------------------------------------------------------------------------
// Kernel 2 R15: R12 base (best, 61.1us) + mask prefetch moved to PROLOGUE.
// R12 post-mortem: in-loop mask loads share vmcnt with the staging DMA, so
// the __syncthreads drains in iters 0..3 waited ~900cy on in-flight HBM mask
// reads -- the tail gain was given back at the barriers.  R14 post-mortem:
// 256^2 4-phase = regression (drain exposed at 1 block/CU); reverted.
// R15: issue all 16 nt int4 mask loads ONCE before the first barrier and
// compress to 16 bits (2 scalar u32) -- one extended first-barrier drain
// (~0.4us, once) instead of four; the 64 MB mask stream overlaps the whole
// ~40us HBM-idle K-loop; epilogue = pure stores + atomics.
// Everything else identical to R12: m97 wave shape (4 waves, 64x64/wave,
// acc[4][4]), 128^2 tile, BK=64 single 32KiB buffer, 2-barrier serial loop,
// granule-XOR LDS layout (row r at 128B stride, granule s at (s^(r&7))*16B),
// XCD-chunked bijective swizzle (FETCH 106->67MB proven), swapped MFMA
// operands (kb first): m = wm+fm*16+(lane&15), n = wn+fn*16+(lane>>4)*4+j.
// __launch_bounds__(256,4) pins VGPR <= 128 (4 blocks/CU) despite the 16
// transient int4 mask regs.
// ---------------------------------------------------------------------------
__global__ void __launch_bounds__(256, 4) attn_gemm_kernel(
    const unsigned short* __restrict__ qn,   // [B*S, D2] bf16
    const unsigned short* __restrict__ kb,   // [B*S, D2] bf16
    const int* __restrict__ mask,            // [B, S, S] int32
    float* __restrict__ attn,                // [B, S, S] f32
    float* __restrict__ rowsum) {            // [B*S] f32 (pre-zeroed)
  __shared__ __align__(16) unsigned short Asm_[8192];   // 16 KiB (single buf)
  __shared__ __align__(16) unsigned short Bsm_[8192];   // 16 KiB

  const int t = threadIdx.x;

  // XCD-chunked swizzle: XCD c owns contiguous work ids [c*128, (c+1)*128)
  // = 8 m-panels x all 16 n-panels (A panel reused 16x inside one L2).
  const int orig = blockIdx.x + 16 * (blockIdx.y + 16 * blockIdx.z);
  const int swz  = (orig & 7) * 128 + (orig >> 3);
  const int bn = (swz & 15) * 128;
  const int bm = ((swz >> 4) & 15) * 128;
  const int bt = swz >> 8;

  // staging base: thread t -> row (t>>3) of each 32-row quarter,
  // permuted granule (t&7)^(row&7)  (row&7 == (t>>3)&7 for all quarters)
  const int srow_ = t >> 3;                 // 0..31
  const int pg_   = (t & 7) ^ (srow_ & 7);
  const unsigned short* gA = qn + ((size_t)bt * S_LEN + bm + srow_) * D2_ + pg_ * 8;
  const unsigned short* gB = kb + ((size_t)bt * S_LEN + bn + srow_) * D2_ + pg_ * 8;
  unsigned short* lA = Asm_ + t * 8;
  unsigned short* lB = Bsm_ + t * 8;

  const int lane = t & 63;
  const int w  = t >> 6;                    // wave 0..3
  const int wm = (w >> 1) * 64;             // wave m offset (0/64)
  const int wn = (w & 1) * 64;              // wave n offset (0/64)
  const int lr = lane & 15;
  const int lg = lane >> 4;

  // stage one 64-wide K-tile (32 KiB total): 4 row-quarters per matrix
  #define STAGE(koff) do {                                          \
      _Pragma("unroll")                                             \
      for (int qq = 0; qq < 4; ++qq) {                              \
        async16(gA + (koff) + (size_t)qq * 32 * D2_, lA + qq * 2048); \
        async16(gB + (koff) + (size_t)qq * 32 * D2_, lB + qq * 2048); \
      }                                                             \
    } while (0)

  f32x4 acc[4][4] = {};           // [fm][fn]

  STAGE(0);                       // tile 0 staging in flight

  // ---- mask prefetch (prologue): 16 nt int4 loads -> 2 u32 of 16 nibbles.
  // Issued before the first barrier: their HBM latency rides under the
  // tile-0 staging drain (one-time cost), and the 64 MB chip-wide mask
  // stream overlaps the HBM-idle K-loop instead of bursting in the tail.
  const int m_base = bm + wm + lr;
  const size_t rb0 = ((size_t)bt * S_LEN) * S_LEN;
  const int n_base = bn + wn + lg * 4;
  unsigned int mklo = 0, mkhi = 0;   // bit (fm*16 + fn*4 + j), fm split lo/hi
  {
    i32x4 tmp[4][4];
    #pragma unroll
    for (int fm = 0; fm < 4; ++fm) {
      const size_t mrow = rb0 + (size_t)(m_base + fm * 16) * S_LEN + n_base;
      #pragma unroll
      for (int fn = 0; fn < 4; ++fn)
        tmp[fm][fn] = __builtin_nontemporal_load((const i32x4*)(mask + mrow + fn * 16));
    }
    #pragma unroll
    for (int fm = 0; fm < 4; ++fm) {
      unsigned int nib4 = 0;
      #pragma unroll
      for (int fn = 0; fn < 4; ++fn) {
        const i32x4 mm = tmp[fm][fn];
        const unsigned int nib = (mm[0] ? 1u : 0u) | (mm[1] ? 2u : 0u) |
                                 (mm[2] ? 4u : 0u) | (mm[3] ? 8u : 0u);
        nib4 |= nib << (fn * 4);
      }
      if (fm < 2) mklo |= nib4 << (fm * 16);
      else        mkhi |= nib4 << ((fm - 2) * 16);
    }
  }

  __syncthreads();   // tile 0 staged (drains vmcnt(0), incl. mask loads once)

  // 16 K-tiles, serial 2-barrier loop; cross-block TLP (4 blocks/CU) fills
  // the drain bubbles (m97 recipe; proven best at this width).
  #pragma unroll 1
  for (int kt = 0; kt < 16; ++kt) {
    #pragma unroll
    for (int ks = 0; ks < 2; ++ks) {
      // K-chunk ks needs granule ks*4+lg: slot ((ks*4+lg) ^ (row&7)), row&7==lr&7
      const int sl = ((ks << 2) + lg) ^ (lr & 7);
      bf16x8 af[4], bfv[4];
      #pragma unroll
      for (int f = 0; f < 4; ++f)
        af[f]  = *(const bf16x8*)(Asm_ + (wm + f * 16 + lr) * 64 + sl * 8);
      #pragma unroll
      for (int f = 0; f < 4; ++f)
        bfv[f] = *(const bf16x8*)(Bsm_ + (wn + f * 16 + lr) * 64 + sl * 8);
      #pragma unroll
      for (int fm = 0; fm < 4; ++fm)
        #pragma unroll
        for (int fn = 0; fn < 4; ++fn)
          acc[fm][fn] = __builtin_amdgcn_mfma_f32_16x16x32_bf16(
              bfv[fn], af[fm], acc[fm][fn], 0, 0, 0);   // swapped order
    }
    __syncthreads();              // all reads of the buffer done
    if (kt < 15) {
      STAGE((kt + 1) * 64);
      __syncthreads();            // staged tile visible
    }
  }

  // epilogue: pure stores (mask already compressed in 2 regs) + rowsum.
  #pragma unroll
  for (int fm = 0; fm < 4; ++fm) {
    const int m = m_base + fm * 16;
    const size_t rowbase = rb0 + (size_t)m * S_LEN;
    const unsigned int bits16 = (fm < 2 ? mklo : mkhi) >> ((fm & 1) * 16);
    float s = 0.f;
    #pragma unroll
    for (int fn = 0; fn < 4; ++fn) {
      const int n0 = bn + wn + fn * 16 + lg * 4;
      const unsigned int nib = (bits16 >> (fn * 4)) & 0xFu;
      f32x4 v;
      v[0] = (nib & 1u) ? 0.0f : acc[fm][fn][0];
      v[1] = (nib & 2u) ? 0.0f : acc[fm][fn][1];
      v[2] = (nib & 4u) ? 0.0f : acc[fm][fn][2];
      v[3] = (nib & 8u) ? 0.0f : acc[fm][fn][3];
      *(f32x4*)(attn + rowbase + n0) = v;
      s += v[0] + v[1] + v[2] + v[3];
    }
    // reduce across the 4 lg groups sharing this row
    s += __shfl_xor(s, 16);
    s += __shfl_xor(s, 32);
    if (lane < 16) atomicAdd(rowsum + (size_t)bt * S_LEN + m, s);
  }
  #undef STAGE
}

// ---------------------------------------------------------------------------
// Kernel 3: out[row,:] = rowsum[row] * w2[:] + fc_b[:] + q[row,:]
// (never touches attn).  Overwrites the out-region that held qn/kb; reads
// nothing from it — safe under stream ordering.
// ---------------------------------------------------------------------------
__global__ void __launch_bounds__(256) out_kernel(
    const float* __restrict__ rowsum, const float* __restrict__ q,
    const float* __restrict__ w2, const float* __restrict__ fcb,
    float* __restrict__ out) {
  const int row = blockIdx.x;
  const int t = threadIdx.x;
  const float rs = rowsum[row];
  const float4 wv = ((const float4*)w2)[t];
  const float4 bv = ((const float4*)fcb)[t];
  const float4 qv = ((const float4*)(q + (size_t)row * D2_))[t];
  float4 o4;
  o4.x = rs * wv.x + bv.x + qv.x;
  o4.y = rs * wv.y + bv.y + qv.y;
  o4.z = rs * wv.z + bv.z + qv.z;
  o4.w = rs * wv.w + bv.w + qv.w;
  ((float4*)(out + (size_t)row * D2_))[t] = o4;
}

// ---------------------------------------------------------------------------
extern "C" void kernel_launch(void* const* d_in, const int* in_sizes, int n_in,
                              void* d_out, int out_size, void* d_ws, size_t ws_size,
                              hipStream_t stream) {
  (void)in_sizes; (void)n_in; (void)out_size; (void)ws_size;
  const float* q    = (const float*)d_in[0];
  const float* k    = (const float*)d_in[1];
  /* d_in[2] == v: provably unused by the reference computation */
  const int*   mask = (const int*)d_in[3];
  const float* V    = (const float*)d_in[4];
  const float* fw   = (const float*)d_in[5];
  const float* fcb  = (const float*)d_in[6];
  const float* lg   = (const float*)d_in[7];
  const float* lb   = (const float*)d_in[8];

  float* out  = (float*)d_out;                          // [B,S,D2]  32 MiB
  float* attn = out + (size_t)NB_ * S_LEN * D2_;        // [B,S,S]   64 MiB

  // qn/kb live INSIDE the out-region (exactly 32 MiB), dead until out_kernel
  // overwrites it last.  d_ws: w2 (4 KiB) + rowsum (32 KiB).
  unsigned short* qn = (unsigned short*)out;                     // 16 MiB
  unsigned short* kb = qn + (size_t)NB_ * S_LEN * D2_;           // 16 MiB
  float* w2     = (float*)d_ws;                                  // 1024 f
  float* rowsum = w2 + D2_;                                      // 8192 f

  prep_kernel<<<NB_ * S_LEN, 256, 0, stream>>>(q, k, lg, lb, V, fw, qn, kb, w2, rowsum);
  attn_gemm_kernel<<<dim3(S_LEN / 128, S_LEN / 128, NB_), 256, 0, stream>>>(qn, kb, mask, attn, rowsum);
  out_kernel<<<NB_ * S_LEN, 256, 0, stream>>>(rowsum, q, w2, fcb, out);
}

// Round 13
// 268.202 us; speedup vs baseline: 1.0352x; 1.0352x over previous
//
#include <hip/hip_runtime.h>
#include <hip/hip_bf16.h>
#include <cstdint>

// Problem constants (B=4, S=2048, D2=1024, DV=64, d_k=64)
#define S_LEN 2048
#define D2_   1024
#define DV_   64
#define NB_   4

typedef __bf16 bf16x8 __attribute__((ext_vector_type(8)));
typedef float  f32x4  __attribute__((ext_vector_type(4)));
typedef int    i32x4  __attribute__((ext_vector_type(4)));

// fp32 -> bf16 round-to-nearest-even
__device__ __forceinline__ unsigned short f2bf(float f) {
  union { float f; unsigned int u; } v; v.f = f;
  unsigned int r = v.u + 0x7fffu + ((v.u >> 16) & 1u);
  return (unsigned short)(r >> 16);
}

// async global->LDS, 16B per lane (global_load_lds_dwordx4)
__device__ __forceinline__ void async16(const unsigned short* g, unsigned short* l) {
  __builtin_amdgcn_global_load_lds(
      (__attribute__((address_space(1))) void*)g,
      (__attribute__((address_space(3))) void*)l,
      16, 0, 0);
}

// ---------------------------------------------------------------------------
// Kernel 1 (fused prep): per row r:
//   qn[r,:] = bf16( LN(q[r,:]) * 0.125 )      (1/sqrt(64) folded in)
//   kb[r,:] = bf16( k[r,:] )
//   blocks 0..3:  w2[d] = fc_w[d,:] . V       (rank-1 collapse of @fc_w.T)
//   blocks 0..31: zero rowsum[] (d_ws is poisoned 0xAA before every launch)
// ---------------------------------------------------------------------------
__global__ void __launch_bounds__(256) prep_kernel(
    const float* __restrict__ q, const float* __restrict__ k,
    const float* __restrict__ gam, const float* __restrict__ bet,
    const float* __restrict__ V, const float* __restrict__ fw,
    unsigned short* __restrict__ qn, unsigned short* __restrict__ kb,
    float* __restrict__ w2, float* __restrict__ rowsum) {
  const int row = blockIdx.x;
  const int t = threadIdx.x;

  if (row < 32) rowsum[row * 256 + t] = 0.0f;   // 8192 floats total

  const float4 x = ((const float4*)(q + (size_t)row * D2_))[t];
  float s  = x.x + x.y + x.z + x.w;
  float ss = x.x * x.x + x.y * x.y + x.z * x.z + x.w * x.w;
  #pragma unroll
  for (int o = 32; o > 0; o >>= 1) { s += __shfl_down(s, o); ss += __shfl_down(ss, o); }
  __shared__ float red[8];
  if ((t & 63) == 0) { red[t >> 6] = s; red[(t >> 6) + 4] = ss; }
  __syncthreads();
  const float tot  = red[0] + red[1] + red[2] + red[3];
  const float tots = red[4] + red[5] + red[6] + red[7];
  const float mu  = tot * (1.0f / D2_);
  const float var = tots * (1.0f / D2_) - mu * mu;
  const float rs  = rsqrtf(var + 1e-6f) * 0.125f;
  const float4 gv = ((const float4*)gam)[t];
  const float4 bv = ((const float4*)bet)[t];
  ushort4 o4;
  o4.x = f2bf((x.x - mu) * rs * gv.x + 0.125f * bv.x);
  o4.y = f2bf((x.y - mu) * rs * gv.y + 0.125f * bv.y);
  o4.z = f2bf((x.z - mu) * rs * gv.z + 0.125f * bv.z);
  o4.w = f2bf((x.w - mu) * rs * gv.w + 0.125f * bv.w);
  ((ushort4*)(qn + (size_t)row * D2_))[t] = o4;

  const float4 kx = ((const float4*)(k + (size_t)row * D2_))[t];
  ushort4 k4;
  k4.x = f2bf(kx.x); k4.y = f2bf(kx.y); k4.z = f2bf(kx.z); k4.w = f2bf(kx.w);
  ((ushort4*)(kb + (size_t)row * D2_))[t] = k4;

  if (row < 4) {
    const int d = row * 256 + t;
    const float4* r  = (const float4*)(fw + (size_t)d * DV_);
    const float4* vv = (const float4*)V;
    float acc = 0.f;
    #pragma unroll
    for (int j = 0; j < 16; ++j) {
      const float4 a = r[j], b = vv[j];
      acc += a.x * b.x + a.y * b.y + a.z * b.z + a.w * b.w;
    }
    w2[d] = acc;
  }
}

// ---------------------------------------------------------------------------
// Kernel 2 R16: R12 base (best, 61.1us) with the mask prefetch spread to
// ONE int4 load per K-iteration.  R15 post-mortem: 16 live int4 (64 VGPR)
// spilled to scratch (WRITE 66->110MB) -- bulk prologue prefetch is
// register-infeasible.  R12 post-mortem: 4-at-once in-loop loads extended
// the iter-0..3 barrier drains (vmcnt shared with staging) and gave back
// the tail savings.  R16: iteration kt loads exactly one int4 (fragment
// fm=kt>>2, fn=kt&3), compressed to a nibble immediately (4 transient VGPR
// + 2 u32 accumulators).  The load is issued at the top of the compute
// phase (~1500cy window) so it lands before that iteration's drain ->
// per-barrier extension ~0; the 64MB phase-locked mask burst moves off the
// serial tail into the HBM-idle K-loop.  Epilogue = pure stores + atomics.
// Everything else identical to R12: m97 wave shape (4 waves, 64x64/wave,
// acc[4][4]), 128^2 tile, BK=64 single 32KiB buffer, 2-barrier serial loop,
// granule-XOR LDS layout (row r at 128B stride, granule s at (s^(r&7))*16B),
// XCD-chunked bijective swizzle, swapped MFMA operands (kb first):
// m = wm+fm*16+(lane&15), n = wn+fn*16+(lane>>4)*4+j.
// ---------------------------------------------------------------------------
__global__ void __launch_bounds__(256, 4) attn_gemm_kernel(
    const unsigned short* __restrict__ qn,   // [B*S, D2] bf16
    const unsigned short* __restrict__ kb,   // [B*S, D2] bf16
    const int* __restrict__ mask,            // [B, S, S] int32
    float* __restrict__ attn,                // [B, S, S] f32
    float* __restrict__ rowsum) {            // [B*S] f32 (pre-zeroed)
  __shared__ __align__(16) unsigned short Asm_[8192];   // 16 KiB (single buf)
  __shared__ __align__(16) unsigned short Bsm_[8192];   // 16 KiB

  const int t = threadIdx.x;

  // XCD-chunked swizzle: XCD c owns contiguous work ids [c*128, (c+1)*128)
  // = 8 m-panels x all 16 n-panels (A panel reused 16x inside one L2).
  const int orig = blockIdx.x + 16 * (blockIdx.y + 16 * blockIdx.z);
  const int swz  = (orig & 7) * 128 + (orig >> 3);
  const int bn = (swz & 15) * 128;
  const int bm = ((swz >> 4) & 15) * 128;
  const int bt = swz >> 8;

  // staging base: thread t -> row (t>>3) of each 32-row quarter,
  // permuted granule (t&7)^(row&7)  (row&7 == (t>>3)&7 for all quarters)
  const int srow_ = t >> 3;                 // 0..31
  const int pg_   = (t & 7) ^ (srow_ & 7);
  const unsigned short* gA = qn + ((size_t)bt * S_LEN + bm + srow_) * D2_ + pg_ * 8;
  const unsigned short* gB = kb + ((size_t)bt * S_LEN + bn + srow_) * D2_ + pg_ * 8;
  unsigned short* lA = Asm_ + t * 8;
  unsigned short* lB = Bsm_ + t * 8;

  const int lane = t & 63;
  const int w  = t >> 6;                    // wave 0..3
  const int wm = (w >> 1) * 64;             // wave m offset (0/64)
  const int wn = (w & 1) * 64;              // wave n offset (0/64)
  const int lr = lane & 15;
  const int lg = lane >> 4;

  // mask geometry for the in-loop compressed prefetch
  const int m_base = bm + wm + lr;
  const size_t rb0 = ((size_t)bt * S_LEN) * S_LEN;
  const int n_base = bn + wn + lg * 4;

  // stage one 64-wide K-tile (32 KiB total): 4 row-quarters per matrix
  #define STAGE(koff) do {                                          \
      _Pragma("unroll")                                             \
      for (int qq = 0; qq < 4; ++qq) {                              \
        async16(gA + (koff) + (size_t)qq * 32 * D2_, lA + qq * 2048); \
        async16(gB + (koff) + (size_t)qq * 32 * D2_, lB + qq * 2048); \
      }                                                             \
    } while (0)

  f32x4 acc[4][4] = {};           // [fm][fn]
  unsigned int mklo = 0, mkhi = 0;   // bit ((fm&1)*16 + fn*4 + j); fm<2 -> lo

  STAGE(0);
  __syncthreads();   // tile 0 staged (drains vmcnt(0))

  // 16 K-tiles, serial 2-barrier loop (m97 recipe, proven best at this
  // width).  Each iteration also streams ONE mask int4 (fragment kt>>2,
  // kt&3) -- issued at the top of the compute phase so its HBM latency is
  // covered before the end-of-compute drain.
  #pragma unroll 1
  for (int kt = 0; kt < 16; ++kt) {
    {
      const int fm = kt >> 2, fn = kt & 3;
      const size_t mrow = rb0 + (size_t)(m_base + fm * 16) * S_LEN + n_base + fn * 16;
      const i32x4 mm = __builtin_nontemporal_load((const i32x4*)(mask + mrow));
      const unsigned int nib = (mm[0] ? 1u : 0u) | (mm[1] ? 2u : 0u) |
                               (mm[2] ? 4u : 0u) | (mm[3] ? 8u : 0u);
      const int sh = (fm & 1) * 16 + fn * 4;
      if (fm < 2) mklo |= nib << sh;
      else        mkhi |= nib << sh;
    }
    #pragma unroll
    for (int ks = 0; ks < 2; ++ks) {
      // K-chunk ks needs granule ks*4+lg: slot ((ks*4+lg) ^ (row&7)), row&7==lr&7
      const int sl = ((ks << 2) + lg) ^ (lr & 7);
      bf16x8 af[4], bfv[4];
      #pragma unroll
      for (int f = 0; f < 4; ++f)
        af[f]  = *(const bf16x8*)(Asm_ + (wm + f * 16 + lr) * 64 + sl * 8);
      #pragma unroll
      for (int f = 0; f < 4; ++f)
        bfv[f] = *(const bf16x8*)(Bsm_ + (wn + f * 16 + lr) * 64 + sl * 8);
      #pragma unroll
      for (int fm = 0; fm < 4; ++fm)
        #pragma unroll
        for (int fn = 0; fn < 4; ++fn)
          acc[fm][fn] = __builtin_amdgcn_mfma_f32_16x16x32_bf16(
              bfv[fn], af[fm], acc[fm][fn], 0, 0, 0);   // swapped order
    }
    __syncthreads();              // all reads of the buffer done
    if (kt < 15) {
      STAGE((kt + 1) * 64);
      __syncthreads();            // staged tile visible
    }
  }

  // epilogue: pure stores (mask compressed in 2 regs) + rowsum reduce.
  #pragma unroll
  for (int fm = 0; fm < 4; ++fm) {
    const int m = m_base + fm * 16;
    const size_t rowbase = rb0 + (size_t)m * S_LEN;
    const unsigned int bits16 = (fm < 2 ? mklo : mkhi) >> ((fm & 1) * 16);
    float s = 0.f;
    #pragma unroll
    for (int fn = 0; fn < 4; ++fn) {
      const int n0 = bn + wn + fn * 16 + lg * 4;
      const unsigned int nib = (bits16 >> (fn * 4)) & 0xFu;
      f32x4 v;
      v[0] = (nib & 1u) ? 0.0f : acc[fm][fn][0];
      v[1] = (nib & 2u) ? 0.0f : acc[fm][fn][1];
      v[2] = (nib & 4u) ? 0.0f : acc[fm][fn][2];
      v[3] = (nib & 8u) ? 0.0f : acc[fm][fn][3];
      *(f32x4*)(attn + rowbase + n0) = v;
      s += v[0] + v[1] + v[2] + v[3];
    }
    // reduce across the 4 lg groups sharing this row
    s += __shfl_xor(s, 16);
    s += __shfl_xor(s, 32);
    if (lane < 16) atomicAdd(rowsum + (size_t)bt * S_LEN + m, s);
  }
  #undef STAGE
}

// ---------------------------------------------------------------------------
// Kernel 3: out[row,:] = rowsum[row] * w2[:] + fc_b[:] + q[row,:]
// (never touches attn).  Overwrites the out-region that held qn/kb; reads
// nothing from it — safe under stream ordering.
// ---------------------------------------------------------------------------
__global__ void __launch_bounds__(256) out_kernel(
    const float* __restrict__ rowsum, const float* __restrict__ q,
    const float* __restrict__ w2, const float* __restrict__ fcb,
    float* __restrict__ out) {
  const int row = blockIdx.x;
  const int t = threadIdx.x;
  const float rs = rowsum[row];
  const float4 wv = ((const float4*)w2)[t];
  const float4 bv = ((const float4*)fcb)[t];
  const float4 qv = ((const float4*)(q + (size_t)row * D2_))[t];
  float4 o4;
  o4.x = rs * wv.x + bv.x + qv.x;
  o4.y = rs * wv.y + bv.y + qv.y;
  o4.z = rs * wv.z + bv.z + qv.z;
  o4.w = rs * wv.w + bv.w + qv.w;
  ((float4*)(out + (size_t)row * D2_))[t] = o4;
}

// ---------------------------------------------------------------------------
extern "C" void kernel_launch(void* const* d_in, const int* in_sizes, int n_in,
                              void* d_out, int out_size, void* d_ws, size_t ws_size,
                              hipStream_t stream) {
  (void)in_sizes; (void)n_in; (void)out_size; (void)ws_size;
  const float* q    = (const float*)d_in[0];
  const float* k    = (const float*)d_in[1];
  /* d_in[2] == v: provably unused by the reference computation */
  const int*   mask = (const int*)d_in[3];
  const float* V    = (const float*)d_in[4];
  const float* fw   = (const float*)d_in[5];
  const float* fcb  = (const float*)d_in[6];
  const float* lg   = (const float*)d_in[7];
  const float* lb   = (const float*)d_in[8];

  float* out  = (float*)d_out;                          // [B,S,D2]  32 MiB
  float* attn = out + (size_t)NB_ * S_LEN * D2_;        // [B,S,S]   64 MiB

  // qn/kb live INSIDE the out-region (exactly 32 MiB), dead until out_kernel
  // overwrites it last.  d_ws: w2 (4 KiB) + rowsum (32 KiB).
  unsigned short* qn = (unsigned short*)out;                     // 16 MiB
  unsigned short* kb = qn + (size_t)NB_ * S_LEN * D2_;           // 16 MiB
  float* w2     = (float*)d_ws;                                  // 1024 f
  float* rowsum = w2 + D2_;                                      // 8192 f

  prep_kernel<<<NB_ * S_LEN, 256, 0, stream>>>(q, k, lg, lb, V, fw, qn, kb, w2, rowsum);
  attn_gemm_kernel<<<dim3(S_LEN / 128, S_LEN / 128, NB_), 256, 0, stream>>>(qn, kb, mask, attn, rowsum);
  out_kernel<<<NB_ * S_LEN, 256, 0, stream>>>(rowsum, q, w2, fcb, out);
}

// Round 14
// 265.356 us; speedup vs baseline: 1.0463x; 1.0107x over previous
//
#include <hip/hip_runtime.h>
#include <hip/hip_bf16.h>
#include <cstdint>

// Problem constants (B=4, S=2048, D2=1024, DV=64, d_k=64)
#define S_LEN 2048
#define D2_   1024
#define DV_   64
#define NB_   4

typedef __bf16 bf16x8 __attribute__((ext_vector_type(8)));
typedef float  f32x4  __attribute__((ext_vector_type(4)));
typedef int    i32x4  __attribute__((ext_vector_type(4)));

// fp32 -> bf16 round-to-nearest-even
__device__ __forceinline__ unsigned short f2bf(float f) {
  union { float f; unsigned int u; } v; v.f = f;
  unsigned int r = v.u + 0x7fffu + ((v.u >> 16) & 1u);
  return (unsigned short)(r >> 16);
}

// async global->LDS, 16B per lane (global_load_lds_dwordx4)
__device__ __forceinline__ void async16(const unsigned short* g, unsigned short* l) {
  __builtin_amdgcn_global_load_lds(
      (__attribute__((address_space(1))) void*)g,
      (__attribute__((address_space(3))) void*)l,
      16, 0, 0);
}

// ---------------------------------------------------------------------------
// Kernel 1 (fused prep): per row r:
//   qn[r,:] = bf16( LN(q[r,:]) * 0.125 )      (1/sqrt(64) folded in)
//   kb[r,:] = bf16( k[r,:] )
//   blocks 0..3:  w2[d] = fc_w[d,:] . V       (rank-1 collapse of @fc_w.T)
//   blocks 0..31: zero rowsum[] (d_ws is poisoned 0xAA before every launch)
// ---------------------------------------------------------------------------
__global__ void __launch_bounds__(256) prep_kernel(
    const float* __restrict__ q, const float* __restrict__ k,
    const float* __restrict__ gam, const float* __restrict__ bet,
    const float* __restrict__ V, const float* __restrict__ fw,
    unsigned short* __restrict__ qn, unsigned short* __restrict__ kb,
    float* __restrict__ w2, float* __restrict__ rowsum) {
  const int row = blockIdx.x;
  const int t = threadIdx.x;

  if (row < 32) rowsum[row * 256 + t] = 0.0f;   // 8192 floats total

  const float4 x = ((const float4*)(q + (size_t)row * D2_))[t];
  float s  = x.x + x.y + x.z + x.w;
  float ss = x.x * x.x + x.y * x.y + x.z * x.z + x.w * x.w;
  #pragma unroll
  for (int o = 32; o > 0; o >>= 1) { s += __shfl_down(s, o); ss += __shfl_down(ss, o); }
  __shared__ float red[8];
  if ((t & 63) == 0) { red[t >> 6] = s; red[(t >> 6) + 4] = ss; }
  __syncthreads();
  const float tot  = red[0] + red[1] + red[2] + red[3];
  const float tots = red[4] + red[5] + red[6] + red[7];
  const float mu  = tot * (1.0f / D2_);
  const float var = tots * (1.0f / D2_) - mu * mu;
  const float rs  = rsqrtf(var + 1e-6f) * 0.125f;
  const float4 gv = ((const float4*)gam)[t];
  const float4 bv = ((const float4*)bet)[t];
  ushort4 o4;
  o4.x = f2bf((x.x - mu) * rs * gv.x + 0.125f * bv.x);
  o4.y = f2bf((x.y - mu) * rs * gv.y + 0.125f * bv.y);
  o4.z = f2bf((x.z - mu) * rs * gv.z + 0.125f * bv.z);
  o4.w = f2bf((x.w - mu) * rs * gv.w + 0.125f * bv.w);
  ((ushort4*)(qn + (size_t)row * D2_))[t] = o4;

  const float4 kx = ((const float4*)(k + (size_t)row * D2_))[t];
  ushort4 k4;
  k4.x = f2bf(kx.x); k4.y = f2bf(kx.y); k4.z = f2bf(kx.z); k4.w = f2bf(kx.w);
  ((ushort4*)(kb + (size_t)row * D2_))[t] = k4;

  if (row < 4) {
    const int d = row * 256 + t;
    const float4* r  = (const float4*)(fw + (size_t)d * DV_);
    const float4* vv = (const float4*)V;
    float acc = 0.f;
    #pragma unroll
    for (int j = 0; j < 16; ++j) {
      const float4 a = r[j], b = vv[j];
      acc += a.x * b.x + a.y * b.y + a.z * b.z + a.w * b.w;
    }
    w2[d] = acc;
  }
}

// ---------------------------------------------------------------------------
// Kernel 2 R17: R12 base (best, 61.1us) with PLAIN (cached) mask loads.
// Mask-placement dose-response (R11 tail / R12 iters0-3 / R16 16-way):
// FETCH 67/76/95 MB, attn 62.0/61.1/66.0 -- spreading nt loads inflates
// HBM fetch (nt bypasses L2 sector merging; neighboring-bn blocks in the
// same XCD re-fetch overlapping mask lines).  R17 keeps R12's placement
// (4 cached int4 loads at the top of iters 0..3, nibble-compressed to 2
// u32s) but drops the nt hint so L2 merges/serves the overlapping sectors.
// Everything else identical to R12: m97 wave shape (4 waves, 64x64/wave,
// acc[4][4]), 128^2 tile, BK=64 single 32KiB buffer, 2-barrier serial loop,
// granule-XOR LDS layout (row r at 128B stride, granule s at (s^(r&7))*16B),
// XCD-chunked bijective swizzle, swapped MFMA operands (kb first):
// m = wm+fm*16+(lane&15), n = wn+fn*16+(lane>>4)*4+j.
// Pre-commit: if attn >= 61us / FETCH unchanged, the structure is at its
// composite ceiling (K-loop at the ~860TF 128^2-structure limit + mandatory
// 128MB mask+attn traffic) -> declare roofline next round.
// ---------------------------------------------------------------------------
__global__ void __launch_bounds__(256, 4) attn_gemm_kernel(
    const unsigned short* __restrict__ qn,   // [B*S, D2] bf16
    const unsigned short* __restrict__ kb,   // [B*S, D2] bf16
    const int* __restrict__ mask,            // [B, S, S] int32
    float* __restrict__ attn,                // [B, S, S] f32
    float* __restrict__ rowsum) {            // [B*S] f32 (pre-zeroed)
  __shared__ __align__(16) unsigned short Asm_[8192];   // 16 KiB (single buf)
  __shared__ __align__(16) unsigned short Bsm_[8192];   // 16 KiB

  const int t = threadIdx.x;

  // XCD-chunked swizzle: XCD c owns contiguous work ids [c*128, (c+1)*128)
  // = 8 m-panels x all 16 n-panels (A panel reused 16x inside one L2).
  const int orig = blockIdx.x + 16 * (blockIdx.y + 16 * blockIdx.z);
  const int swz  = (orig & 7) * 128 + (orig >> 3);
  const int bn = (swz & 15) * 128;
  const int bm = ((swz >> 4) & 15) * 128;
  const int bt = swz >> 8;

  // staging base: thread t -> row (t>>3) of each 32-row quarter,
  // permuted granule (t&7)^(row&7)  (row&7 == (t>>3)&7 for all quarters)
  const int srow_ = t >> 3;                 // 0..31
  const int pg_   = (t & 7) ^ (srow_ & 7);
  const unsigned short* gA = qn + ((size_t)bt * S_LEN + bm + srow_) * D2_ + pg_ * 8;
  const unsigned short* gB = kb + ((size_t)bt * S_LEN + bn + srow_) * D2_ + pg_ * 8;
  unsigned short* lA = Asm_ + t * 8;
  unsigned short* lB = Bsm_ + t * 8;

  const int lane = t & 63;
  const int w  = t >> 6;                    // wave 0..3
  const int wm = (w >> 1) * 64;             // wave m offset (0/64)
  const int wn = (w & 1) * 64;              // wave n offset (0/64)
  const int lr = lane & 15;
  const int lg = lane >> 4;

  // mask geometry (used inside the K-loop for the compressed prefetch)
  const int m_base = bm + wm + lr;
  const size_t rb0 = ((size_t)bt * S_LEN) * S_LEN;
  const int n_base = bn + wn + lg * 4;

  // stage one 64-wide K-tile (32 KiB total): 4 row-quarters per matrix
  #define STAGE(koff) do {                                          \
      _Pragma("unroll")                                             \
      for (int qq = 0; qq < 4; ++qq) {                              \
        async16(gA + (koff) + (size_t)qq * 32 * D2_, lA + qq * 2048); \
        async16(gB + (koff) + (size_t)qq * 32 * D2_, lB + qq * 2048); \
      }                                                             \
    } while (0)

  f32x4 acc[4][4] = {};           // [fm][fn]
  unsigned int mklo = 0, mkhi = 0;   // 16 nibbles: bit (fm*16+fn*4+j), fm split lo/hi

  STAGE(0);
  __syncthreads();   // tile 0 staged (drains vmcnt(0))

  // 16 K-tiles, serial 2-barrier loop; cross-block TLP (4 blocks/CU) fills
  // the drain bubbles.  Iterations 0..3 additionally stream one fm-group of
  // the mask (4 CACHED int4 loads -> one nibble each) into mklo/mkhi -- the
  // 64 MB mask read rides the BW-idle K-loop window instead of the tail.
  #pragma unroll 1
  for (int kt = 0; kt < 16; ++kt) {
    if (kt < 4) {
      const int fm = kt;
      const size_t mrow = rb0 + (size_t)(m_base + fm * 16) * S_LEN + n_base;
      unsigned int nib4 = 0;
      #pragma unroll
      for (int fn = 0; fn < 4; ++fn) {
        const i32x4 mm = *(const i32x4*)(mask + mrow + fn * 16);
        const unsigned int nib = (mm[0] ? 1u : 0u) | (mm[1] ? 2u : 0u) |
                                 (mm[2] ? 4u : 0u) | (mm[3] ? 8u : 0u);
        nib4 |= nib << (fn * 4);
      }
      if (fm < 2) mklo |= nib4 << (fm * 16);
      else        mkhi |= nib4 << ((fm - 2) * 16);
    }
    #pragma unroll
    for (int ks = 0; ks < 2; ++ks) {
      // K-chunk ks needs granule ks*4+lg: slot ((ks*4+lg) ^ (row&7)), row&7==lr&7
      const int sl = ((ks << 2) + lg) ^ (lr & 7);
      bf16x8 af[4], bfv[4];
      #pragma unroll
      for (int f = 0; f < 4; ++f)
        af[f]  = *(const bf16x8*)(Asm_ + (wm + f * 16 + lr) * 64 + sl * 8);
      #pragma unroll
      for (int f = 0; f < 4; ++f)
        bfv[f] = *(const bf16x8*)(Bsm_ + (wn + f * 16 + lr) * 64 + sl * 8);
      #pragma unroll
      for (int fm = 0; fm < 4; ++fm)
        #pragma unroll
        for (int fn = 0; fn < 4; ++fn)
          acc[fm][fn] = __builtin_amdgcn_mfma_f32_16x16x32_bf16(
              bfv[fn], af[fm], acc[fm][fn], 0, 0, 0);   // swapped order
    }
    __syncthreads();              // all reads of the buffer done
    if (kt < 15) {
      STAGE((kt + 1) * 64);
      __syncthreads();            // staged tile visible
    }
  }

  // epilogue: pure stores (mask already compressed in 2 regs) + rowsum.
  #pragma unroll
  for (int fm = 0; fm < 4; ++fm) {
    const int m = m_base + fm * 16;
    const size_t rowbase = rb0 + (size_t)m * S_LEN;
    const unsigned int bits16 = (fm < 2 ? mklo : mkhi) >> ((fm & 1) * 16);
    float s = 0.f;
    #pragma unroll
    for (int fn = 0; fn < 4; ++fn) {
      const int n0 = bn + wn + fn * 16 + lg * 4;
      const unsigned int nib = (bits16 >> (fn * 4)) & 0xFu;
      f32x4 v;
      v[0] = (nib & 1u) ? 0.0f : acc[fm][fn][0];
      v[1] = (nib & 2u) ? 0.0f : acc[fm][fn][1];
      v[2] = (nib & 4u) ? 0.0f : acc[fm][fn][2];
      v[3] = (nib & 8u) ? 0.0f : acc[fm][fn][3];
      *(f32x4*)(attn + rowbase + n0) = v;
      s += v[0] + v[1] + v[2] + v[3];
    }
    // reduce across the 4 lg groups sharing this row
    s += __shfl_xor(s, 16);
    s += __shfl_xor(s, 32);
    if (lane < 16) atomicAdd(rowsum + (size_t)bt * S_LEN + m, s);
  }
  #undef STAGE
}

// ---------------------------------------------------------------------------
// Kernel 3: out[row,:] = rowsum[row] * w2[:] + fc_b[:] + q[row,:]
// (never touches attn).  Overwrites the out-region that held qn/kb; reads
// nothing from it — safe under stream ordering.
// ---------------------------------------------------------------------------
__global__ void __launch_bounds__(256) out_kernel(
    const float* __restrict__ rowsum, const float* __restrict__ q,
    const float* __restrict__ w2, const float* __restrict__ fcb,
    float* __restrict__ out) {
  const int row = blockIdx.x;
  const int t = threadIdx.x;
  const float rs = rowsum[row];
  const float4 wv = ((const float4*)w2)[t];
  const float4 bv = ((const float4*)fcb)[t];
  const float4 qv = ((const float4*)(q + (size_t)row * D2_))[t];
  float4 o4;
  o4.x = rs * wv.x + bv.x + qv.x;
  o4.y = rs * wv.y + bv.y + qv.y;
  o4.z = rs * wv.z + bv.z + qv.z;
  o4.w = rs * wv.w + bv.w + qv.w;
  ((float4*)(out + (size_t)row * D2_))[t] = o4;
}

// ---------------------------------------------------------------------------
extern "C" void kernel_launch(void* const* d_in, const int* in_sizes, int n_in,
                              void* d_out, int out_size, void* d_ws, size_t ws_size,
                              hipStream_t stream) {
  (void)in_sizes; (void)n_in; (void)out_size; (void)ws_size;
  const float* q    = (const float*)d_in[0];
  const float* k    = (const float*)d_in[1];
  /* d_in[2] == v: provably unused by the reference computation */
  const int*   mask = (const int*)d_in[3];
  const float* V    = (const float*)d_in[4];
  const float* fw   = (const float*)d_in[5];
  const float* fcb  = (const float*)d_in[6];
  const float* lg   = (const float*)d_in[7];
  const float* lb   = (const float*)d_in[8];

  float* out  = (float*)d_out;                          // [B,S,D2]  32 MiB
  float* attn = out + (size_t)NB_ * S_LEN * D2_;        // [B,S,S]   64 MiB

  // qn/kb live INSIDE the out-region (exactly 32 MiB), dead until out_kernel
  // overwrites it last.  d_ws: w2 (4 KiB) + rowsum (32 KiB).
  unsigned short* qn = (unsigned short*)out;                     // 16 MiB
  unsigned short* kb = qn + (size_t)NB_ * S_LEN * D2_;           // 16 MiB
  float* w2     = (float*)d_ws;                                  // 1024 f
  float* rowsum = w2 + D2_;                                      // 8192 f

  prep_kernel<<<NB_ * S_LEN, 256, 0, stream>>>(q, k, lg, lb, V, fw, qn, kb, w2, rowsum);
  attn_gemm_kernel<<<dim3(S_LEN / 128, S_LEN / 128, NB_), 256, 0, stream>>>(qn, kb, mask, attn, rowsum);
  out_kernel<<<NB_ * S_LEN, 256, 0, stream>>>(rowsum, q, w2, fcb, out);
}

// Round 16
// 263.999 us; speedup vs baseline: 1.0516x; 1.0051x over previous
//
#include <hip/hip_runtime.h>
#include <hip/hip_bf16.h>
#include <cstdint>

// Problem constants (B=4, S=2048, D2=1024, DV=64, d_k=64)
#define S_LEN 2048
#define D2_   1024
#define DV_   64
#define NB_   4

typedef __bf16 bf16x8 __attribute__((ext_vector_type(8)));
typedef float  f32x4  __attribute__((ext_vector_type(4)));
typedef int    i32x4  __attribute__((ext_vector_type(4)));

// fp32 -> bf16 round-to-nearest-even
__device__ __forceinline__ unsigned short f2bf(float f) {
  union { float f; unsigned int u; } v; v.f = f;
  unsigned int r = v.u + 0x7fffu + ((v.u >> 16) & 1u);
  return (unsigned short)(r >> 16);
}

// async global->LDS, 16B per lane (global_load_lds_dwordx4)
__device__ __forceinline__ void async16(const unsigned short* g, unsigned short* l) {
  __builtin_amdgcn_global_load_lds(
      (__attribute__((address_space(1))) void*)g,
      (__attribute__((address_space(3))) void*)l,
      16, 0, 0);
}

// ---------------------------------------------------------------------------
// Kernel 1 (fused prep): per row r:
//   qn[r,:] = bf16( LN(q[r,:]) * 0.125 )      (1/sqrt(64) folded in)
//   kb[r,:] = bf16( k[r,:] )
//   blocks 0..3:  w2[d] = fc_w[d,:] . V       (rank-1 collapse of @fc_w.T)
//   blocks 0..31: zero rowsum[] (d_ws is poisoned 0xAA before every launch)
// ---------------------------------------------------------------------------
__global__ void __launch_bounds__(256) prep_kernel(
    const float* __restrict__ q, const float* __restrict__ k,
    const float* __restrict__ gam, const float* __restrict__ bet,
    const float* __restrict__ V, const float* __restrict__ fw,
    unsigned short* __restrict__ qn, unsigned short* __restrict__ kb,
    float* __restrict__ w2, float* __restrict__ rowsum) {
  const int row = blockIdx.x;
  const int t = threadIdx.x;

  if (row < 32) rowsum[row * 256 + t] = 0.0f;   // 8192 floats total

  const float4 x = ((const float4*)(q + (size_t)row * D2_))[t];
  float s  = x.x + x.y + x.z + x.w;
  float ss = x.x * x.x + x.y * x.y + x.z * x.z + x.w * x.w;
  #pragma unroll
  for (int o = 32; o > 0; o >>= 1) { s += __shfl_down(s, o); ss += __shfl_down(ss, o); }
  __shared__ float red[8];
  if ((t & 63) == 0) { red[t >> 6] = s; red[(t >> 6) + 4] = ss; }
  __syncthreads();
  const float tot  = red[0] + red[1] + red[2] + red[3];
  const float tots = red[4] + red[5] + red[6] + red[7];
  const float mu  = tot * (1.0f / D2_);
  const float var = tots * (1.0f / D2_) - mu * mu;
  const float rs  = rsqrtf(var + 1e-6f) * 0.125f;
  const float4 gv = ((const float4*)gam)[t];
  const float4 bv = ((const float4*)bet)[t];
  ushort4 o4;
  o4.x = f2bf((x.x - mu) * rs * gv.x + 0.125f * bv.x);
  o4.y = f2bf((x.y - mu) * rs * gv.y + 0.125f * bv.y);
  o4.z = f2bf((x.z - mu) * rs * gv.z + 0.125f * bv.z);
  o4.w = f2bf((x.w - mu) * rs * gv.w + 0.125f * bv.w);
  ((ushort4*)(qn + (size_t)row * D2_))[t] = o4;

  const float4 kx = ((const float4*)(k + (size_t)row * D2_))[t];
  ushort4 k4;
  k4.x = f2bf(kx.x); k4.y = f2bf(kx.y); k4.z = f2bf(kx.z); k4.w = f2bf(kx.w);
  ((ushort4*)(kb + (size_t)row * D2_))[t] = k4;

  if (row < 4) {
    const int d = row * 256 + t;
    const float4* r  = (const float4*)(fw + (size_t)d * DV_);
    const float4* vv = (const float4*)V;
    float acc = 0.f;
    #pragma unroll
    for (int j = 0; j < 16; ++j) {
      const float4 a = r[j], b = vv[j];
      acc += a.x * b.x + a.y * b.y + a.z * b.z + a.w * b.w;
    }
    w2[d] = acc;
  }
}

// ---------------------------------------------------------------------------
// Kernel 2 R18 = R12 exact revert (session best: attn 61.1us, total 265.07).
// Mask-placement dose-response closed (R11/R12/R16/R17: nt-tail 62.0 /
// nt-iters0-3 61.1 / nt-16-way 66.0 / cached-iters0-3 67.4) -- R12's
// configuration is the measured minimum.  Structural attempts all regressed:
// R9 syncthreads-dbuf 71.7, R13 counted-vmcnt 70.9, R14 256^2 4-phase 66-68,
// R15 bulk mask prefetch 75.6 (VGPR spill).  This 128^2 m97-shape 2-barrier
// loop is at its documented ~860TF structure ceiling; the tail carries the
// mandatory 64MB mask read + 64MB attn write.
// Structure: m97 wave shape (4 waves, 64x64/wave, acc[4][4]), 128^2 tile,
// BK=64 single 32KiB buffer, 2-barrier serial loop, granule-XOR LDS layout
// (row r at 128B stride, granule s at (s^(r&7))*16B; staging thread t ->
// row-quarter q*32+(t>>3), dest t*16B + q*2048, global granule (t&7)^(row&7)),
// XCD-chunked bijective swizzle, nt mask loads in iters 0..3 (one fm-group
// of 4 int4 -> nibble-compressed into 2 u32), swapped MFMA operands (kb
// first): m = wm+fm*16+(lane&15), n = wn+fn*16+(lane>>4)*4+j.
// ---------------------------------------------------------------------------
__global__ void __launch_bounds__(256, 4) attn_gemm_kernel(
    const unsigned short* __restrict__ qn,   // [B*S, D2] bf16
    const unsigned short* __restrict__ kb,   // [B*S, D2] bf16
    const int* __restrict__ mask,            // [B, S, S] int32
    float* __restrict__ attn,                // [B, S, S] f32
    float* __restrict__ rowsum) {            // [B*S] f32 (pre-zeroed)
  __shared__ __align__(16) unsigned short Asm_[8192];   // 16 KiB (single buf)
  __shared__ __align__(16) unsigned short Bsm_[8192];   // 16 KiB

  const int t = threadIdx.x;

  // XCD-chunked swizzle: XCD c owns contiguous work ids [c*128, (c+1)*128)
  // = 8 m-panels x all 16 n-panels (A panel reused 16x inside one L2).
  const int orig = blockIdx.x + 16 * (blockIdx.y + 16 * blockIdx.z);
  const int swz  = (orig & 7) * 128 + (orig >> 3);
  const int bn = (swz & 15) * 128;
  const int bm = ((swz >> 4) & 15) * 128;
  const int bt = swz >> 8;

  // staging base: thread t -> row (t>>3) of each 32-row quarter,
  // permuted granule (t&7)^(row&7)  (row&7 == (t>>3)&7 for all quarters)
  const int srow_ = t >> 3;                 // 0..31
  const int pg_   = (t & 7) ^ (srow_ & 7);
  const unsigned short* gA = qn + ((size_t)bt * S_LEN + bm + srow_) * D2_ + pg_ * 8;
  const unsigned short* gB = kb + ((size_t)bt * S_LEN + bn + srow_) * D2_ + pg_ * 8;
  unsigned short* lA = Asm_ + t * 8;
  unsigned short* lB = Bsm_ + t * 8;

  const int lane = t & 63;
  const int w  = t >> 6;                    // wave 0..3
  const int wm = (w >> 1) * 64;             // wave m offset (0/64)
  const int wn = (w & 1) * 64;              // wave n offset (0/64)
  const int lr = lane & 15;
  const int lg = lane >> 4;

  // mask geometry (used inside the K-loop for the compressed prefetch)
  const int m_base = bm + wm + lr;
  const size_t rb0 = ((size_t)bt * S_LEN) * S_LEN;
  const int n_base = bn + wn + lg * 4;

  // stage one 64-wide K-tile (32 KiB total): 4 row-quarters per matrix
  #define STAGE(koff) do {                                          \
      _Pragma("unroll")                                             \
      for (int qq = 0; qq < 4; ++qq) {                              \
        async16(gA + (koff) + (size_t)qq * 32 * D2_, lA + qq * 2048); \
        async16(gB + (koff) + (size_t)qq * 32 * D2_, lB + qq * 2048); \
      }                                                             \
    } while (0)

  f32x4 acc[4][4] = {};           // [fm][fn]
  unsigned int mklo = 0, mkhi = 0;   // 16 nibbles: bit (fm*16+fn*4+j), fm split lo/hi

  STAGE(0);
  __syncthreads();   // tile 0 staged (drains vmcnt(0))

  // 16 K-tiles, serial 2-barrier loop; cross-block TLP (4 blocks/CU) fills
  // the drain bubbles.  Iterations 0..3 additionally stream one fm-group of
  // the mask (4 nt int4 loads -> one nibble each) into mklo/mkhi -- the
  // 64 MB mask read rides the BW-idle K-loop window instead of the tail.
  #pragma unroll 1
  for (int kt = 0; kt < 16; ++kt) {
    if (kt < 4) {
      const int fm = kt;
      const size_t mrow = rb0 + (size_t)(m_base + fm * 16) * S_LEN + n_base;
      unsigned int nib4 = 0;
      #pragma unroll
      for (int fn = 0; fn < 4; ++fn) {
        const i32x4 mm = __builtin_nontemporal_load((const i32x4*)(mask + mrow + fn * 16));
        const unsigned int nib = (mm[0] ? 1u : 0u) | (mm[1] ? 2u : 0u) |
                                 (mm[2] ? 4u : 0u) | (mm[3] ? 8u : 0u);
        nib4 |= nib << (fn * 4);
      }
      if (fm < 2) mklo |= nib4 << (fm * 16);
      else        mkhi |= nib4 << ((fm - 2) * 16);
    }
    #pragma unroll
    for (int ks = 0; ks < 2; ++ks) {
      // K-chunk ks needs granule ks*4+lg: slot ((ks*4+lg) ^ (row&7)), row&7==lr&7
      const int sl = ((ks << 2) + lg) ^ (lr & 7);
      bf16x8 af[4], bfv[4];
      #pragma unroll
      for (int f = 0; f < 4; ++f)
        af[f]  = *(const bf16x8*)(Asm_ + (wm + f * 16 + lr) * 64 + sl * 8);
      #pragma unroll
      for (int f = 0; f < 4; ++f)
        bfv[f] = *(const bf16x8*)(Bsm_ + (wn + f * 16 + lr) * 64 + sl * 8);
      #pragma unroll
      for (int fm = 0; fm < 4; ++fm)
        #pragma unroll
        for (int fn = 0; fn < 4; ++fn)
          acc[fm][fn] = __builtin_amdgcn_mfma_f32_16x16x32_bf16(
              bfv[fn], af[fm], acc[fm][fn], 0, 0, 0);   // swapped order
    }
    __syncthreads();              // all reads of the buffer done
    if (kt < 15) {
      STAGE((kt + 1) * 64);
      __syncthreads();            // staged tile visible
    }
  }

  // epilogue: pure stores (mask already compressed in 2 regs) + rowsum.
  #pragma unroll
  for (int fm = 0; fm < 4; ++fm) {
    const int m = m_base + fm * 16;
    const size_t rowbase = rb0 + (size_t)m * S_LEN;
    const unsigned int bits16 = (fm < 2 ? mklo : mkhi) >> ((fm & 1) * 16);
    float s = 0.f;
    #pragma unroll
    for (int fn = 0; fn < 4; ++fn) {
      const int n0 = bn + wn + fn * 16 + lg * 4;
      const unsigned int nib = (bits16 >> (fn * 4)) & 0xFu;
      f32x4 v;
      v[0] = (nib & 1u) ? 0.0f : acc[fm][fn][0];
      v[1] = (nib & 2u) ? 0.0f : acc[fm][fn][1];
      v[2] = (nib & 4u) ? 0.0f : acc[fm][fn][2];
      v[3] = (nib & 8u) ? 0.0f : acc[fm][fn][3];
      *(f32x4*)(attn + rowbase + n0) = v;
      s += v[0] + v[1] + v[2] + v[3];
    }
    // reduce across the 4 lg groups sharing this row
    s += __shfl_xor(s, 16);
    s += __shfl_xor(s, 32);
    if (lane < 16) atomicAdd(rowsum + (size_t)bt * S_LEN + m, s);
  }
  #undef STAGE
}

// ---------------------------------------------------------------------------
// Kernel 3: out[row,:] = rowsum[row] * w2[:] + fc_b[:] + q[row,:]
// (never touches attn).  Overwrites the out-region that held qn/kb; reads
// nothing from it — safe under stream ordering.
// ---------------------------------------------------------------------------
__global__ void __launch_bounds__(256) out_kernel(
    const float* __restrict__ rowsum, const float* __restrict__ q,
    const float* __restrict__ w2, const float* __restrict__ fcb,
    float* __restrict__ out) {
  const int row = blockIdx.x;
  const int t = threadIdx.x;
  const float rs = rowsum[row];
  const float4 wv = ((const float4*)w2)[t];
  const float4 bv = ((const float4*)fcb)[t];
  const float4 qv = ((const float4*)(q + (size_t)row * D2_))[t];
  float4 o4;
  o4.x = rs * wv.x + bv.x + qv.x;
  o4.y = rs * wv.y + bv.y + qv.y;
  o4.z = rs * wv.z + bv.z + qv.z;
  o4.w = rs * wv.w + bv.w + qv.w;
  ((float4*)(out + (size_t)row * D2_))[t] = o4;
}

// ---------------------------------------------------------------------------
extern "C" void kernel_launch(void* const* d_in, const int* in_sizes, int n_in,
                              void* d_out, int out_size, void* d_ws, size_t ws_size,
                              hipStream_t stream) {
  (void)in_sizes; (void)n_in; (void)out_size; (void)ws_size;
  const float* q    = (const float*)d_in[0];
  const float* k    = (const float*)d_in[1];
  /* d_in[2] == v: provably unused by the reference computation */
  const int*   mask = (const int*)d_in[3];
  const float* V    = (const float*)d_in[4];
  const float* fw   = (const float*)d_in[5];
  const float* fcb  = (const float*)d_in[6];
  const float* lg   = (const float*)d_in[7];
  const float* lb   = (const float*)d_in[8];

  float* out  = (float*)d_out;                          // [B,S,D2]  32 MiB
  float* attn = out + (size_t)NB_ * S_LEN * D2_;        // [B,S,S]   64 MiB

  // qn/kb live INSIDE the out-region (exactly 32 MiB), dead until out_kernel
  // overwrites it last.  d_ws: w2 (4 KiB) + rowsum (32 KiB).
  unsigned short* qn = (unsigned short*)out;                     // 16 MiB
  unsigned short* kb = qn + (size_t)NB_ * S_LEN * D2_;           // 16 MiB
  float* w2     = (float*)d_ws;                                  // 1024 f
  float* rowsum = w2 + D2_;                                      // 8192 f

  prep_kernel<<<NB_ * S_LEN, 256, 0, stream>>>(q, k, lg, lb, V, fw, qn, kb, w2, rowsum);
  attn_gemm_kernel<<<dim3(S_LEN / 128, S_LEN / 128, NB_), 256, 0, stream>>>(qn, kb, mask, attn, rowsum);
  out_kernel<<<NB_ * S_LEN, 256, 0, stream>>>(rowsum, q, w2, fcb, out);
}